// Round 1
// baseline (7960.000 us; speedup 1.0000x reference)
//
#include <hip/hip_runtime.h>
#include <hip/hip_bf16.h>

typedef __bf16 bf16x8 __attribute__((ext_vector_type(8)));
typedef float f32x4 __attribute__((ext_vector_type(4)));
typedef unsigned short u16;

#define GLD_LDS16(gp, lp) __builtin_amdgcn_global_load_lds( \
    (const __attribute__((address_space(1))) unsigned int*)(gp), \
    (__attribute__((address_space(3))) unsigned int*)(lp), 16, 0, 0)

__device__ __forceinline__ float tanh_fast(float x) {
  // tanh(x) = 1 - 2/(e^{2x}+1); saturates correctly for |x| large.
  float e = __expf(2.0f * x);
  return 1.0f - __fdividef(2.0f, e + 1.0f);
}

__device__ __forceinline__ u16 bf16_rn(float x) {
  union { float f; unsigned u; } v; v.f = x;
  unsigned r = v.u + 0x7fffu + ((v.u >> 16) & 1u);
  return (u16)(r >> 16);
}

// ---------------------------------------------------------------------------
// Fused GEMM: C[M,N] = A[M,K] (bf16, row-major) x Bt[N,K]^T (bf16, row-major)
// m97 structure: BM=128, BK=64, 256 threads (4 waves, 2x2), 16x16x32 bf16 MFMA,
// global_load_lds width-16 staging, fp32 accumulation, fused epilogue.
// MODE 0: out_bf = bf16(tanh(acc + bias + t*wt))            (hidden)
// MODE 1: v = 0.999*y_in + 0.001*z_in + h*(acc + bias); out32 = v; out_bf = v
// MODE 2: v = z_in + h*(acc + bias);               out32 = v; out_bf = v
// ---------------------------------------------------------------------------
template <int BN, int K, int MODE>
__global__ __launch_bounds__(256)
void gemm_fused(const u16* __restrict__ A, const u16* __restrict__ Bt,
                const float* __restrict__ bias, const float* __restrict__ wt,
                float tval,
                const float* __restrict__ y_in, const float* __restrict__ z_in,
                float* __restrict__ out32, u16* __restrict__ out_bf, int N) {
  constexpr int BM = 128, BK = 64;
  constexpr int WTN = BN / 2;       // per-wave N extent (2x2 wave grid)
  constexpr int FN = WTN / 16;      // N fragments per wave
  constexpr int ACH = BM * BK * 2 / 1024;  // 16 x 1KB chunks
  constexpr int BCH = BN * BK * 2 / 1024;  // 16 or 8

  __shared__ u16 As[BM * BK];
  __shared__ u16 Bs[BN * BK];

  const int tid = threadIdx.x;
  const int wave = tid >> 6;
  const int lane = tid & 63;
  const int wm = wave >> 1, wn = wave & 1;
  const int l15 = lane & 15, kg = lane >> 4;

  const int bn0 = blockIdx.x * BN;
  const int bm0 = blockIdx.y * BM;

  f32x4 acc[4][FN];
#pragma unroll
  for (int m = 0; m < 4; ++m)
#pragma unroll
    for (int n = 0; n < FN; ++n) acc[m][n] = (f32x4){0.f, 0.f, 0.f, 0.f};

  const int sr = lane >> 3;       // row within 8-row (1KB) chunk
  const int sc = (lane & 7) * 8;  // col (element) offset within row

  const u16* Ag = A + (size_t)bm0 * K;
  const u16* Bg = Bt + (size_t)bn0 * K;

  for (int kt = 0; kt < K / BK; ++kt) {
    const u16* Ak = Ag + kt * BK;
    const u16* Bk = Bg + kt * BK;
#pragma unroll
    for (int i = 0; i < ACH / 4; ++i) {
      const int ch = wave + i * 4;
      GLD_LDS16(Ak + (size_t)(ch * 8 + sr) * K + sc, (char*)As + ch * 1024);
    }
#pragma unroll
    for (int i = 0; i < BCH / 4; ++i) {
      const int ch = wave + i * 4;
      GLD_LDS16(Bk + (size_t)(ch * 8 + sr) * K + sc, (char*)Bs + ch * 1024);
    }
    __syncthreads();
#pragma unroll
    for (int ks = 0; ks < 2; ++ks) {
      bf16x8 af[4], bf[FN];
#pragma unroll
      for (int m = 0; m < 4; ++m)
        af[m] = *reinterpret_cast<const bf16x8*>(
            &As[(wm * 64 + m * 16 + l15) * BK + ks * 32 + kg * 8]);
#pragma unroll
      for (int n = 0; n < FN; ++n)
        bf[n] = *reinterpret_cast<const bf16x8*>(
            &Bs[(wn * WTN + n * 16 + l15) * BK + ks * 32 + kg * 8]);
#pragma unroll
      for (int m = 0; m < 4; ++m)
#pragma unroll
        for (int n = 0; n < FN; ++n)
          acc[m][n] =
              __builtin_amdgcn_mfma_f32_16x16x32_bf16(af[m], bf[n], acc[m][n], 0, 0, 0);
    }
    __syncthreads();
  }

  // Epilogue. C/D layout (verified, m89/m91): col = lane&15, row = (lane>>4)*4 + reg.
#pragma unroll
  for (int n = 0; n < FN; ++n) {
    const int col = bn0 + wn * WTN + n * 16 + l15;
    const float bv = bias[col];
    const float wv = (MODE == 0) ? wt[col] : 0.f;
#pragma unroll
    for (int m = 0; m < 4; ++m) {
      const int row0 = bm0 + wm * 64 + m * 16 + kg * 4;
#pragma unroll
      for (int r = 0; r < 4; ++r) {
        const size_t idx = (size_t)(row0 + r) * N + col;
        const float a = acc[m][n][r];
        if (MODE == 0) {
          const float x = a + bv + tval * wv;
          out_bf[idx] = bf16_rn(tanh_fast(x));
        } else if (MODE == 1) {
          const float v = 0.999f * y_in[idx] + 0.001f * z_in[idx] +
                          0.015625f * (a + bv);
          out32[idx] = v;
          out_bf[idx] = bf16_rn(v);
        } else {
          const float v = z_in[idx] + 0.015625f * (a + bv);
          out32[idx] = v;
          out_bf[idx] = bf16_rn(v);
        }
      }
    }
  }
}

// in: [R, C] f32  ->  out: [C, R] bf16 (LDS-tiled transpose, both sides coalesced)
__global__ void transpose_bf16(const float* __restrict__ in, u16* __restrict__ out,
                               int R, int C) {
  __shared__ float tile[32][33];
  const int bx = blockIdx.x * 32;  // C block
  const int by = blockIdx.y * 32;  // R block
  const int tx = threadIdx.x, ty = threadIdx.y;  // 32 x 8
#pragma unroll
  for (int i = 0; i < 32; i += 8)
    tile[ty + i][tx] = in[(size_t)(by + ty + i) * C + (bx + tx)];
  __syncthreads();
#pragma unroll
  for (int i = 0; i < 32; i += 8)
    out[(size_t)(bx + ty + i) * R + (by + tx)] = bf16_rn(tile[tx][ty + i]);
}

__global__ void init_state(const float* __restrict__ y0, float* __restrict__ y32,
                           float* __restrict__ z32, u16* __restrict__ zbf, int n) {
  const int i = blockIdx.x * blockDim.x + threadIdx.x;
  if (i < n) {
    const float v = y0[i];
    y32[i] = v;
    z32[i] = v;
    zbf[i] = bf16_rn(v);
  }
}

extern "C" void kernel_launch(void* const* d_in, const int* in_sizes, int n_in,
                              void* d_out, int out_size, void* d_ws, size_t ws_size,
                              hipStream_t stream) {
  const float* y0 = (const float*)d_in[0];
  const float* W1 = (const float*)d_in[1];  // [512, 2048]
  const float* b1 = (const float*)d_in[2];  // [2048]
  const float* wt = (const float*)d_in[3];  // [2048]
  const float* W2 = (const float*)d_in[4];  // [2048, 512]
  const float* b2 = (const float*)d_in[5];  // [512]

  constexpr int B = 4096, D = 512, HID = 2048, NSTEP = 64;
  constexpr float Hh = 1.0f / 64.0f;

  char* ws = (char*)d_ws;
  u16* W1t = (u16*)ws; ws += (size_t)HID * D * 2;   // [2048][512] bf16
  u16* W2t = (u16*)ws; ws += (size_t)D * HID * 2;   // [512][2048] bf16
  u16* hid = (u16*)ws; ws += (size_t)B * HID * 2;   // [4096][2048] bf16
  float* z32 = (float*)ws; ws += (size_t)B * D * 4; // [4096][512] f32
  u16* ybf = (u16*)ws; ws += (size_t)B * D * 2;
  u16* zbf = (u16*)ws; ws += (size_t)B * D * 2;
  float* y32 = (float*)d_out;                        // y state lives in d_out

  // W1 [D,HID] -> W1t [HID,D];  W2 [HID,D] -> W2t [D,HID]
  transpose_bf16<<<dim3(HID / 32, D / 32), dim3(32, 8), 0, stream>>>(W1, W1t, D, HID);
  transpose_bf16<<<dim3(D / 32, HID / 32), dim3(32, 8), 0, stream>>>(W2, W2t, HID, D);
  init_state<<<(B * D + 255) / 256, 256, 0, stream>>>(y0, y32, z32, zbf, B * D);

  for (int s = 0; s < NSTEP; ++s) {
    const float t0 = (float)s * Hh;
    const float t1 = (float)(s + 1) * Hh;
    // hidden = tanh(z @ W1 + b1 + t0*wt)
    gemm_fused<128, 512, 0><<<dim3(HID / 128, B / 128), 256, 0, stream>>>(
        zbf, W1t, b1, wt, t0, nullptr, nullptr, nullptr, hid, HID);
    // y = 0.999*y + 0.001*z + h*(hidden @ W2 + b2)
    gemm_fused<64, 2048, 1><<<dim3(D / 64, B / 128), 256, 0, stream>>>(
        hid, W2t, b2, nullptr, 0.f, y32, z32, y32, ybf, D);
    // hidden = tanh(y @ W1 + b1 + t1*wt)
    gemm_fused<128, 512, 0><<<dim3(HID / 128, B / 128), 256, 0, stream>>>(
        ybf, W1t, b1, wt, t1, nullptr, nullptr, nullptr, hid, HID);
    // z = z + h*(hidden @ W2 + b2)
    gemm_fused<64, 2048, 2><<<dim3(D / 64, B / 128), 256, 0, stream>>>(
        hid, W2t, b2, nullptr, 0.f, nullptr, z32, z32, zbf, D);
  }
}